// Round 7
// baseline (1015.404 us; speedup 1.0000x reference)
//
#include <hip/hip_runtime.h>
#include <hip/hip_fp16.h>

#define NB   256
#define TT   1024
#define II   64
#define NT   768

typedef _Float16 f16;
typedef _Float16 hf8 __attribute__((ext_vector_type(8)));
typedef float    ff4 __attribute__((ext_vector_type(4)));

__device__ __forceinline__ float rcp_fast(float x){
    float r; asm("v_rcp_f32 %0, %1" : "=v"(r) : "v"(x)); return r;
}
__device__ __forceinline__ float sigm(float x){
    return rcp_fast(1.0f + __expf(-x));
}
__device__ __forceinline__ float tanh_f(float x){
    x = fminf(10.0f, fmaxf(-10.0f, x));
    float e = __expf(2.0f * x);
    return (e - 1.0f) * rcp_fast(e + 1.0f);
}

// 48 M-tiles of 16 rows, GATE-INTERLEAVED: tile row rho <-> (unit 4*tau+(rho>>2),
// gate rho&3).  Tiles 0-31: L1 (units 0-127, K=192 over [x;h1]).
// Tiles 32-47: L2 (units 0-63, K=192 over [h1;h2]).
// C/D: col=lane&15, row=(lane>>4)*4+reg [m89] => lane's 4 acc regs of tile
// sel=(rho>>2) hold gates i,f,g,o of unit 4*tau+kg. In-lane activation.
// x pipeline: depth-4 LDS ring + 2-deep register queue in wave 8; load for
// x[t+4] issued at step t, published at t+2, consumed at t+4 -> HBM latency
// never on the step critical path.

__launch_bounds__(NT, 3)
__global__ void lstm_mfma(const float* __restrict__ x,
                          const float* __restrict__ Wih1, const float* __restrict__ Whh1,
                          const float* __restrict__ bih1, const float* __restrict__ bhh1,
                          const float* __restrict__ Wih2, const float* __restrict__ Whh2,
                          const float* __restrict__ bih2, const float* __restrict__ bhh2,
                          const float* __restrict__ W1,   const float* __restrict__ b1,
                          const float* __restrict__ W2,   const float* __restrict__ b2,
                          float* __restrict__ out)
{
    __shared__ __align__(16) f16 xring[4][II];    // x_t in slot t&3
    __shared__ __align__(16) f16 h1buf[2][128];
    __shared__ __align__(16) f16 h2buf[2][64];
    __shared__ float headbuf[32];

    const int j    = threadIdx.x;      // 0..767
    const int b    = blockIdx.x;
    const int wave = j >> 6;           // 0..11
    const int lane = j & 63;
    const int rho  = lane & 15;
    const int kg   = lane >> 4;        // 0..3
    const bool l2w = (wave >= 8);

    // ---------- one-time: A fragments (f16, interleaved rows), biases ----------
    hf8 A[4][6];
    ff4 bias[4];
    #pragma unroll
    for (int i = 0; i < 4; ++i){
        const int tau = 4*wave + i;
        #pragma unroll
        for (int kt = 0; kt < 6; ++kt){
            const int k = 32*kt + kg*8;
            const float* src;
            if (!l2w){
                const int R = (rho & 3)*128 + 4*tau + (rho >> 2);
                src = (k < 64) ? (Wih1 + R*64 + k) : (Whh1 + R*128 + (k - 64));
            } else {
                const int R = (rho & 3)*64 + 4*(tau - 32) + (rho >> 2);
                src = (k < 128) ? (Wih2 + R*128 + k) : (Whh2 + R*64 + (k - 128));
            }
            float4 v0 = *(const float4*)src;
            float4 v1 = *(const float4*)(src + 4);
            hf8 a;
            a[0]=(f16)v0.x; a[1]=(f16)v0.y; a[2]=(f16)v0.z; a[3]=(f16)v0.w;
            a[4]=(f16)v1.x; a[5]=(f16)v1.y; a[6]=(f16)v1.z; a[7]=(f16)v1.w;
            A[i][kt] = a;
        }
        if (!l2w){
            #pragma unroll
            for (int r = 0; r < 4; ++r){
                const int R = r*128 + 4*tau + kg;
                bias[i][r] = bih1[R] + bhh1[R];
            }
        } else {
            #pragma unroll
            for (int r = 0; r < 4; ++r){
                const int R = r*64 + 4*(tau - 32) + kg;
                bias[i][r] = bih2[R] + bhh2[R];
            }
        }
    }

    const int  sel    = rho >> 2;                       // which of my 4 tiles
    const int  myU    = 4*(4*wave + sel - (l2w ? 32 : 0)) + kg;
    const bool writer = ((lane & 3) == 0);
    float c = 0.0f;

    const float* xb = x + (size_t)b * TT * II;

    // prologue: x[0],x[1] -> ring slots 0,1; h1,h2 zero; ldA=x[2], ldB=x[3]
    if (j < 128)                  xring[j >> 6][j & 63] = (f16)xb[j];
    else if (j < 256)             h1buf[0][j - 128] = (f16)0.0f;
    else if (j < 320)             h2buf[0][j - 256] = (f16)0.0f;
    float ldA = 0.0f, ldB = 0.0f;
    if (wave == 8){
        ldA = xb[2*II + lane];
        ldB = xb[3*II + lane];
    }
    __syncthreads();

    int cur = 0;
    for (int t = 0; t < TT; ++t){
        // wave 8: issue load for x[t+4]; publish x[t+2] (loaded 2 steps ago)
        float ldN = 0.0f;
        if (wave == 8){
            int tn = t + 4; if (tn > TT-1) tn = TT-1;
            ldN = xb[tn*II + lane];
            xring[(t + 2) & 3][lane] = (f16)ldA;
        }

        const f16* xr  = xring[t & 3];
        const f16* h1c = h1buf[cur];
        const f16* h2c = h2buf[cur];

        // ---- MFMA: preacts for L1(step t) / L2(step t-1) ----
        ff4 a0 = bias[0], a1 = bias[1], a2 = bias[2], a3 = bias[3];
        #pragma unroll
        for (int kt = 0; kt < 6; ++kt){
            const f16* bp;
            if (!l2w) bp = (kt < 2) ? (xr  + 32*kt       + kg*8)
                                    : (h1c + 32*(kt - 2) + kg*8);
            else      bp = (kt < 4) ? (h1c + 32*kt       + kg*8)
                                    : (h2c + 32*(kt - 4) + kg*8);
            hf8 bf = *(const hf8*)bp;
            a0 = __builtin_amdgcn_mfma_f32_16x16x32_f16(A[0][kt], bf, a0, 0, 0, 0);
            a1 = __builtin_amdgcn_mfma_f32_16x16x32_f16(A[1][kt], bf, a1, 0, 0, 0);
            a2 = __builtin_amdgcn_mfma_f32_16x16x32_f16(A[2][kt], bf, a2, 0, 0, 0);
            a3 = __builtin_amdgcn_mfma_f32_16x16x32_f16(A[3][kt], bf, a3, 0, 0, 0);
        }

        // ---- in-lane activation for this lane's unit ----
        ff4 a = (sel >= 2) ? ((sel & 1) ? a3 : a2) : ((sel & 1) ? a1 : a0);
        float hv;
        if (l2w && t == 0){
            hv = 0.0f;                       // h2_{-1} = 0, c2 untouched
        } else {
            float ig = sigm(a[0]);
            float fg = sigm(a[1]);
            float gg = tanh_f(a[2]);
            float og = sigm(a[3]);
            c  = fg*c + ig*gg;
            hv = og * tanh_f(c);
        }
        if (writer){
            if (l2w) h2buf[cur ^ 1][myU] = (f16)hv;
            else     h1buf[cur ^ 1][myU] = (f16)hv;
        }
        if (wave == 8){ ldA = ldB; ldB = ldN; }
        __syncthreads();
        cur ^= 1;
    }
    // after loop: cur == 0; h1buf[0]=h1_{TT-1}, h2buf[0]=h2_{TT-2}

    // ---- epilogue: L2 step TT-1 ----
    if (l2w){
        const f16* h1c = h1buf[0];
        const f16* h2c = h2buf[0];
        ff4 a0 = bias[0], a1 = bias[1], a2 = bias[2], a3 = bias[3];
        #pragma unroll
        for (int kt = 0; kt < 6; ++kt){
            const f16* bp = (kt < 4) ? (h1c + 32*kt + kg*8)
                                     : (h2c + 32*(kt - 4) + kg*8);
            hf8 bf = *(const hf8*)bp;
            a0 = __builtin_amdgcn_mfma_f32_16x16x32_f16(A[0][kt], bf, a0, 0, 0, 0);
            a1 = __builtin_amdgcn_mfma_f32_16x16x32_f16(A[1][kt], bf, a1, 0, 0, 0);
            a2 = __builtin_amdgcn_mfma_f32_16x16x32_f16(A[2][kt], bf, a2, 0, 0, 0);
            a3 = __builtin_amdgcn_mfma_f32_16x16x32_f16(A[3][kt], bf, a3, 0, 0, 0);
        }
        ff4 a = (sel >= 2) ? ((sel & 1) ? a3 : a2) : ((sel & 1) ? a1 : a0);
        float ig = sigm(a[0]);
        float fg = sigm(a[1]);
        float gg = tanh_f(a[2]);
        float og = sigm(a[3]);
        c = fg*c + ig*gg;
        float hv = og * tanh_f(c);
        if (writer) h2buf[1][myU] = (f16)hv;
    }
    __syncthreads();

    // ---- MLP head (final h2 in h2buf[1]) ----
    if (j < 32){
        float a = b1[j];
        const float* w = W1 + j*64;
        #pragma unroll
        for (int k = 0; k < 64; ++k) a = fmaf(w[k], (float)h2buf[1][k], a);
        headbuf[j] = sigm(a);
    }
    __syncthreads();
    if (j == 0){
        float a = b2[0];
        #pragma unroll
        for (int k = 0; k < 32; ++k) a = fmaf(W2[k], headbuf[k], a);
        out[b] = sigm(a);
    }
}

extern "C" void kernel_launch(void* const* d_in, const int* in_sizes, int n_in,
                              void* d_out, int out_size, void* d_ws, size_t ws_size,
                              hipStream_t stream)
{
    (void)in_sizes; (void)n_in; (void)d_ws; (void)ws_size; (void)out_size;
    lstm_mfma<<<NB, NT, 0, stream>>>(
        (const float*)d_in[0],
        (const float*)d_in[1], (const float*)d_in[2],
        (const float*)d_in[3], (const float*)d_in[4],
        (const float*)d_in[5], (const float*)d_in[6],
        (const float*)d_in[7], (const float*)d_in[8],
        (const float*)d_in[9], (const float*)d_in[10],
        (const float*)d_in[11], (const float*)d_in[12],
        (float*)d_out);
}

// Round 8
// 1014.253 us; speedup vs baseline: 1.0011x; 1.0011x over previous
//
#include <hip/hip_runtime.h>
#include <hip/hip_fp16.h>

#define NB   256
#define TT   1024
#define II   64
#define NT   768

typedef _Float16 f16;
typedef _Float16 f16x4 __attribute__((ext_vector_type(4)));
typedef _Float16 hf8 __attribute__((ext_vector_type(8)));
typedef float    ff4 __attribute__((ext_vector_type(4)));

__device__ __forceinline__ float rcp_fast(float x){
    float r; asm("v_rcp_f32 %0, %1" : "=v"(r) : "v"(x)); return r;
}
__device__ __forceinline__ float exp2_fast(float x){
    float r; asm("v_exp_f32 %0, %1" : "=v"(r) : "v"(x)); return r;
}
// sigm(x) = rcp(1 + 2^(-log2e*x));  x->-inf: rcp(inf)=0, x->+inf: rcp(1)=1
__device__ __forceinline__ float sigm(float x){
    return rcp_fast(1.0f + exp2_fast(x * -1.44269504f));
}
// tanh(x) = 1 - 2*rcp(1 + 2^(2*log2e*x)); inf-safe both directions, no clamp
__device__ __forceinline__ float tanh_f(float x){
    return fmaf(-2.0f, rcp_fast(1.0f + exp2_fast(x * 2.88539008f)), 1.0f);
}

// 48 M-tiles of 16 rows, GATE-INTERLEAVED: tile row rho <-> (unit 4*tau+(rho>>2),
// gate rho&3).  Tiles 0-31: L1 (units 0-127, K=192 over [x;h1]).
// Tiles 32-47: L2 (units 0-63, K=192 over [h1;h2]).
// C/D: col=lane&15, row=(lane>>4)*4+reg [m89] => lane's 4 acc regs of tile
// sel=(rho>>2) hold gates i,f,g,o of unit 4*tau+kg. In-lane activation.
// x pipeline: LDS chunk buffer xchunk[64][64] f16 (two 32-step halves,
// row = t&63). Once per 32 steps, 8 waves stage the next 32 steps of x
// (issue float4 loads early, cvt+ds_write after the step's compute) ->
// exposed HBM latency ~900cyc/32steps instead of per-step.

__launch_bounds__(NT, 3)
__global__ void lstm_mfma(const float* __restrict__ x,
                          const float* __restrict__ Wih1, const float* __restrict__ Whh1,
                          const float* __restrict__ bih1, const float* __restrict__ bhh1,
                          const float* __restrict__ Wih2, const float* __restrict__ Whh2,
                          const float* __restrict__ bih2, const float* __restrict__ bhh2,
                          const float* __restrict__ W1,   const float* __restrict__ b1,
                          const float* __restrict__ W2,   const float* __restrict__ b2,
                          float* __restrict__ out)
{
    __shared__ __align__(16) f16 xchunk[64][II];   // 8 KB: x_t in row t&63
    __shared__ __align__(16) f16 h1buf[2][128];
    __shared__ __align__(16) f16 h2buf[2][64];
    __shared__ float headbuf[32];

    const int j    = threadIdx.x;      // 0..767
    const int b    = blockIdx.x;
    const int wave = j >> 6;           // 0..11
    const int lane = j & 63;
    const int rho  = lane & 15;
    const int kg   = lane >> 4;        // 0..3
    const bool l2w = (wave >= 8);

    // ---------- one-time: A fragments (f16, interleaved rows), biases ----------
    hf8 A[4][6];
    ff4 bias[4];
    #pragma unroll
    for (int i = 0; i < 4; ++i){
        const int tau = 4*wave + i;
        #pragma unroll
        for (int kt = 0; kt < 6; ++kt){
            const int k = 32*kt + kg*8;
            const float* src;
            if (!l2w){
                const int R = (rho & 3)*128 + 4*tau + (rho >> 2);
                src = (k < 64) ? (Wih1 + R*64 + k) : (Whh1 + R*128 + (k - 64));
            } else {
                const int R = (rho & 3)*64 + 4*(tau - 32) + (rho >> 2);
                src = (k < 128) ? (Wih2 + R*128 + k) : (Whh2 + R*64 + (k - 128));
            }
            float4 v0 = *(const float4*)src;
            float4 v1 = *(const float4*)(src + 4);
            hf8 a;
            a[0]=(f16)v0.x; a[1]=(f16)v0.y; a[2]=(f16)v0.z; a[3]=(f16)v0.w;
            a[4]=(f16)v1.x; a[5]=(f16)v1.y; a[6]=(f16)v1.z; a[7]=(f16)v1.w;
            A[i][kt] = a;
        }
        if (!l2w){
            #pragma unroll
            for (int r = 0; r < 4; ++r){
                const int R = r*128 + 4*tau + kg;
                bias[i][r] = bih1[R] + bhh1[R];
            }
        } else {
            #pragma unroll
            for (int r = 0; r < 4; ++r){
                const int R = r*64 + 4*(tau - 32) + kg;
                bias[i][r] = bih2[R] + bhh2[R];
            }
        }
    }

    const int  sel    = rho >> 2;
    const int  myU    = 4*(4*wave + sel - (l2w ? 32 : 0)) + kg;
    const bool writer = ((lane & 3) == 0);
    float c = 0.0f;

    const float* xb = x + (size_t)b * TT * II;

    // prologue: stage chunk 0 (steps 0..31 -> rows 0..31); zero h1,h2
    if (j < 512){
        float4 v = ((const float4*)xb)[j];
        f16x4 w; w[0]=(f16)v.x; w[1]=(f16)v.y; w[2]=(f16)v.z; w[3]=(f16)v.w;
        *(f16x4*)&xchunk[j >> 4][(j & 15)*4] = w;
    } else if (j < 640){
        h1buf[0][j - 512] = (f16)0.0f;
    } else if (j < 704){
        h2buf[0][j - 640] = (f16)0.0f;
    }
    __syncthreads();

    int cur = 0;
    for (int t = 0; t < TT; ++t){
        // staging: once per 32 steps, 8 waves load next chunk (issue early)
        const bool do_stage = ((t & 31) == 0) && (t + 32 < TT) && (j < 512);
        float4 sv;
        if (do_stage)
            sv = ((const float4*)(xb + (size_t)(t + 32)*II))[j];

        const f16* xr  = xchunk[t & 63];
        const f16* h1c = h1buf[cur];
        const f16* h2c = h2buf[cur];

        // ---- MFMA: preacts for L1(step t) / L2(step t-1) ----
        ff4 a0 = bias[0], a1 = bias[1], a2 = bias[2], a3 = bias[3];
        #pragma unroll
        for (int kt = 0; kt < 6; ++kt){
            const f16* bp;
            if (!l2w) bp = (kt < 2) ? (xr  + 32*kt       + kg*8)
                                    : (h1c + 32*(kt - 2) + kg*8);
            else      bp = (kt < 4) ? (h1c + 32*kt       + kg*8)
                                    : (h2c + 32*(kt - 4) + kg*8);
            hf8 bf = *(const hf8*)bp;
            a0 = __builtin_amdgcn_mfma_f32_16x16x32_f16(A[0][kt], bf, a0, 0, 0, 0);
            a1 = __builtin_amdgcn_mfma_f32_16x16x32_f16(A[1][kt], bf, a1, 0, 0, 0);
            a2 = __builtin_amdgcn_mfma_f32_16x16x32_f16(A[2][kt], bf, a2, 0, 0, 0);
            a3 = __builtin_amdgcn_mfma_f32_16x16x32_f16(A[3][kt], bf, a3, 0, 0, 0);
        }

        // ---- in-lane activation for this lane's unit ----
        ff4 a = (sel >= 2) ? ((sel & 1) ? a3 : a2) : ((sel & 1) ? a1 : a0);
        float hv;
        if (l2w && t == 0){
            hv = 0.0f;                       // h2_{-1} = 0, c2 untouched
        } else {
            float ig = sigm(a[0]);
            float fg = sigm(a[1]);
            float gg = tanh_f(a[2]);
            float og = sigm(a[3]);
            c  = fg*c + ig*gg;
            hv = og * tanh_f(c);
        }
        if (writer){
            if (l2w) h2buf[cur ^ 1][myU] = (f16)hv;
            else     h1buf[cur ^ 1][myU] = (f16)hv;
        }

        // staging publish (wait lands here, overlapped with the step's work)
        if (do_stage){
            f16x4 w; w[0]=(f16)sv.x; w[1]=(f16)sv.y; w[2]=(f16)sv.z; w[3]=(f16)sv.w;
            *(f16x4*)&xchunk[((t + 32) & 63) + (j >> 4)][(j & 15)*4] = w;
        }
        __syncthreads();
        cur ^= 1;
    }
    // after loop: cur == 0; h1buf[0]=h1_{TT-1}, h2buf[0]=h2_{TT-2}

    // ---- epilogue: L2 step TT-1 ----
    if (l2w){
        const f16* h1c = h1buf[0];
        const f16* h2c = h2buf[0];
        ff4 a0 = bias[0], a1 = bias[1], a2 = bias[2], a3 = bias[3];
        #pragma unroll
        for (int kt = 0; kt < 6; ++kt){
            const f16* bp = (kt < 4) ? (h1c + 32*kt + kg*8)
                                     : (h2c + 32*(kt - 4) + kg*8);
            hf8 bf = *(const hf8*)bp;
            a0 = __builtin_amdgcn_mfma_f32_16x16x32_f16(A[0][kt], bf, a0, 0, 0, 0);
            a1 = __builtin_amdgcn_mfma_f32_16x16x32_f16(A[1][kt], bf, a1, 0, 0, 0);
            a2 = __builtin_amdgcn_mfma_f32_16x16x32_f16(A[2][kt], bf, a2, 0, 0, 0);
            a3 = __builtin_amdgcn_mfma_f32_16x16x32_f16(A[3][kt], bf, a3, 0, 0, 0);
        }
        ff4 a = (sel >= 2) ? ((sel & 1) ? a3 : a2) : ((sel & 1) ? a1 : a0);
        float ig = sigm(a[0]);
        float fg = sigm(a[1]);
        float gg = tanh_f(a[2]);
        float og = sigm(a[3]);
        c = fg*c + ig*gg;
        float hv = og * tanh_f(c);
        if (writer) h2buf[1][myU] = (f16)hv;
    }
    __syncthreads();

    // ---- MLP head (final h2 in h2buf[1]) ----
    if (j < 32){
        float a = b1[j];
        const float* w = W1 + j*64;
        #pragma unroll
        for (int k = 0; k < 64; ++k) a = fmaf(w[k], (float)h2buf[1][k], a);
        headbuf[j] = sigm(a);
    }
    __syncthreads();
    if (j == 0){
        float a = b2[0];
        #pragma unroll
        for (int k = 0; k < 32; ++k) a = fmaf(W2[k], headbuf[k], a);
        out[b] = sigm(a);
    }
}

extern "C" void kernel_launch(void* const* d_in, const int* in_sizes, int n_in,
                              void* d_out, int out_size, void* d_ws, size_t ws_size,
                              hipStream_t stream)
{
    (void)in_sizes; (void)n_in; (void)d_ws; (void)ws_size; (void)out_size;
    lstm_mfma<<<NB, NT, 0, stream>>>(
        (const float*)d_in[0],
        (const float*)d_in[1], (const float*)d_in[2],
        (const float*)d_in[3], (const float*)d_in[4],
        (const float*)d_in[5], (const float*)d_in[6],
        (const float*)d_in[7], (const float*)d_in[8],
        (const float*)d_in[9], (const float*)d_in[10],
        (const float*)d_in[11], (const float*)d_in[12],
        (float*)d_out);
}